// Round 1
// 195.112 us; speedup vs baseline: 1.0090x; 1.0090x over previous
//
#include <hip/hip_runtime.h>
#include <stdint.h>

// Cost volume: out[b,k,h,w] = (1/81) * sum_c x1[b,c,h,w] * x2[b,c,h-i,w-j]
// k = (9i+j) mod 81, i,j in [-4,4], zero-padded x2. B=4 C=128 H=128 W=256 fp32.
//
// R6: latency-bound fix (was: MfmaUtil 4%, VALUBusy 15%, HBM 33%, 9.7M LDS
// bank-conflict cycles -> nothing saturated).
//  - Double-buffered LDS staging (2 x 25792 ush = 103 KB): stage chunk k+1
//    while computing chunk k; ONE barrier per chunk (6 total vs 9).
//    1 block/CU (16 waves) instead of 2 - pipeline replaces cross-block TLP.
//  - Two register load sets ping-pong: loads for chunk k+2 issued at iter k,
//    consumed at iter k+1's convert -> load-to-use distance = full iteration
//    (covers ~900cy HBM latency; before: only the ~10-MFMA compute phase).
//  - v_cvt_pk_bf16_f32 (RNE, identical rounding to the old bit-trick):
//    1 VALU per packed c-pair word instead of ~9.
//  - Epilogue scratch kk-stride 16 -> 20 floats: scatter banks 20*ja+m are
//    ~2-way instead of ~4.5-way (the 9.7M conflict source); readback float4
//    stays 16B-aligned (20 floats = 80 B).
//  - s_setprio(1) around MFMA cluster (waves now have convert/compute role
//    diversity within an iteration).
//
// Toeplitz window: D[m][n] = sum_c x1[c, w0+m] * x2[c, h-i, w0-4+n]
//   -> out(w0+m, j) = D[m][m+4-j], window 24 cols = 2x mfma_f32_16x16x32_bf16.
// Block: 1024 thr = 16 waves = (hl 0..7) x (igrp 0..1); tile 8h x 16w.
// LDS staging layout per buffer (ushorts): A: [8 hl][16 m][32k + 8 pad = 40],
//   row 648; B: [16 h2][32 wcol][40], row 1288; buffer = 25792 ush.

#define HH 128
#define WW 256
#define HW 32768
#define DD 81
#define NT 1024

typedef __attribute__((ext_vector_type(8))) short short8;
typedef __attribute__((ext_vector_type(4))) float float4v;

// staging geometry (ushorts)
#define A_ROW 648   // 16 m * 40 + 8 pad
#define B_ROW 1288  // 32 wcol * 40 + 8 pad
#define KSTR 40     // 32 bf16 + 8 pad
#define B_BASE 5184 // A region = 8 * 648
#define PER_BUF 25792  // ushorts per buffer (51584 B)
// epilogue scratch: [8 hl][81 kk][20 floats]  (kk-stride 20 = bank fix)
#define EP_K 20
#define EP_H 1620   // 81 * 20

__device__ __forceinline__ uint32_t cvt_pk_bf16(float lo, float hi) {
  uint32_t r;
  asm("v_cvt_pk_bf16_f32 %0, %1, %2" : "=v"(r) : "v"(lo), "v"(hi));
  return r;
}

template <int NI, int I0>
__device__ __forceinline__ void compute_chunk(const unsigned short* buf, int hl,
                                              int n16, int quad, float4v* acc0,
                                              float4v* acc1) {
  const short8 a = *(const short8*)(buf + hl * A_ROW + n16 * KSTR + quad * 8);
  __builtin_amdgcn_s_setprio(1);
#pragma unroll
  for (int ii = 0; ii < NI; ++ii) {
    const int row = hl - (I0 + ii) + 4;  // 0..15
    const unsigned short* bp = buf + B_BASE + row * B_ROW + n16 * KSTR + quad * 8;
    const short8 b0 = *(const short8*)(bp);
    const short8 b1 = *(const short8*)(bp + 16 * KSTR);
    acc0[ii] = __builtin_amdgcn_mfma_f32_16x16x32_bf16(a, b0, acc0[ii], 0, 0, 0);
    acc1[ii] = __builtin_amdgcn_mfma_f32_16x16x32_bf16(a, b1, acc1[ii], 0, 0, 0);
  }
  __builtin_amdgcn_s_setprio(0);
}

__global__ __launch_bounds__(NT, 4) void cost_volume_kernel(
    const float* __restrict__ x1, const float* __restrict__ x2,
    float* __restrict__ out, const float* __restrict__ zws) {
  __shared__ unsigned short smem[2 * PER_BUF];  // 103168 B, 1 block/CU

  const int b = blockIdx.z;
  const int h0 = blockIdx.y * 8;
  const int w0 = blockIdx.x * 16;
  const int t = threadIdx.x;
  const int wid = t >> 6;
  const int hl = wid & 7;
  const int igrp = wid >> 3;
  const int lane = t & 63;
  const int n16 = lane & 15;
  const int quad = lane >> 4;

  const float* x1b = x1 + (size_t)b * 128 * HW;
  const float* x2b = x2 + (size_t)b * 128 * HW;

  // ---- decode this thread's two staging tasks (chunk-invariant parts) ----
  const float* tbase[2];
  int tgoff[2], tlds[2], tcp[2];
  bool tok[2];
#pragma unroll
  for (int s = 0; s < 2; ++s) {
    const int tau = t + s * NT;
    if (tau < 512) {
      const int cp = tau >> 5, rem = tau & 31, row = rem >> 2, f4 = rem & 3;
      tbase[s] = x1b;
      tgoff[s] = (h0 + row) * WW + w0 + f4 * 4;
      tlds[s] = row * A_ROW + f4 * 160 + 2 * cp;
      tcp[s] = cp;
      tok[s] = true;
    } else {
      const int tp = tau - 512;  // 0..1535
      const int cp = tp / 96, rem = tp - cp * 96, row = rem / 6,
                f4 = rem - row * 6;
      const int h2 = h0 - 4 + row;
      const int wg = w0 - 4 + f4 * 4;
      tbase[s] = x2b;
      tgoff[s] = h2 * WW + wg;
      tlds[s] = B_BASE + row * B_ROW + f4 * 160 + 2 * cp;
      tcp[s] = cp;
      tok[s] = ((unsigned)h2 < (unsigned)HH) && ((unsigned)wg <= (unsigned)(WW - 4));
    }
  }

  float4v acc0[5], acc1[5];
#pragma unroll
  for (int ii = 0; ii < 5; ++ii) {
    acc0[ii] = (float4v){0.f, 0.f, 0.f, 0.f};
    acc1[ii] = (float4v){0.f, 0.f, 0.f, 0.f};
  }

  float4 va0[2], vb0[2], va1[2], vb1[2];

#define LOADSET(VA, VB, C0)                                                    \
  {                                                                            \
    _Pragma("unroll") for (int s = 0; s < 2; ++s) {                            \
      const float* p =                                                         \
          tok[s] ? tbase[s] + (size_t)((C0) + 2 * tcp[s]) * HW + tgoff[s]      \
                 : zws;                                                        \
      const float* q = tok[s] ? p + HW : zws;                                  \
      VA[s] = *(const float4*)p;                                               \
      VB[s] = *(const float4*)q;                                               \
    }                                                                          \
  }

#define CONVSET(VA, VB, BUFSEL)                                                \
  {                                                                            \
    _Pragma("unroll") for (int s = 0; s < 2; ++s) {                            \
      unsigned short* dst = smem + (BUFSEL) * PER_BUF + tlds[s];               \
      const float4 fa = VA[s];                                                 \
      const float4 fb = VB[s];                                                 \
      *(uint32_t*)(dst + 0 * KSTR) = cvt_pk_bf16(fa.x, fb.x);                  \
      *(uint32_t*)(dst + 1 * KSTR) = cvt_pk_bf16(fa.y, fb.y);                  \
      *(uint32_t*)(dst + 2 * KSTR) = cvt_pk_bf16(fa.z, fb.z);                  \
      *(uint32_t*)(dst + 3 * KSTR) = cvt_pk_bf16(fa.w, fb.w);                  \
    }                                                                          \
  }

#define COMPUTE(BUFSEL)                                                        \
  {                                                                            \
    const unsigned short* cbuf = smem + (BUFSEL) * PER_BUF;                    \
    if (igrp == 0)                                                             \
      compute_chunk<5, -4>(cbuf, hl, n16, quad, acc0, acc1);                   \
    else                                                                       \
      compute_chunk<4, 1>(cbuf, hl, n16, quad, acc0, acc1);                    \
  }

  // ---- software-pipelined main loop: 4 chunks of 32 channels ----
  // prologue: c0, c1 in flight; c0 staged into buf0
  LOADSET(va0, vb0, 0);
  LOADSET(va1, vb1, 32);
  CONVSET(va0, vb0, 0);
  __syncthreads();  // buf0 visible

  // k=0: loads c2 issued; compute c0 (buf0); stage c1 -> buf1
  LOADSET(va0, vb0, 64);
  COMPUTE(0);
  CONVSET(va1, vb1, 1);
  __syncthreads();

  // k=1: loads c3 issued; compute c1 (buf1); stage c2 -> buf0
  //      (buf0's chunk-0 reads completed before the k=0 barrier)
  LOADSET(va1, vb1, 96);
  COMPUTE(1);
  CONVSET(va0, vb0, 0);
  __syncthreads();

  // k=2: compute c2 (buf0); stage c3 -> buf1
  COMPUTE(0);
  CONVSET(va1, vb1, 1);
  __syncthreads();

  // k=3: compute c3 (buf1)
  COMPUTE(1);
  __syncthreads();  // all compute reads done; reuse smem as fp32 scratch

  // ---- epilogue: scatter D-fragments to LDS scratch, read back coalesced ---
  float* scratch = (float*)smem;  // 8*1620 = 12960 floats = 51840 B
  const float sc = 1.0f / 81.0f;
  const int ni = igrp ? 4 : 5;
  const int i0 = igrp ? 1 : -4;
#pragma unroll 5
  for (int ii = 0; ii < 5; ++ii) {
    if (ii >= ni) break;
    const int iabs = (i0 + ii) + 4;
    const float av0[4] = {acc0[ii].x, acc0[ii].y, acc0[ii].z, acc0[ii].w};
    const float av1[4] = {acc1[ii].x, acc1[ii].y, acc1[ii].z, acc1[ii].w};
#pragma unroll
    for (int reg = 0; reg < 4; ++reg) {
      const int m = quad * 4 + reg;
      // tile0: window col n16 -> j = m + 4 - n16
      {
        const unsigned ja = (unsigned)(m + 4 - n16 + 4);
        if (ja < 9u)
          scratch[hl * EP_H + (iabs * 9 + (int)ja) * EP_K + m] = av0[reg] * sc;
      }
      // tile1: window col 16+n16 -> j = m - 12 - n16
      {
        const unsigned ja = (unsigned)(m - 12 - n16 + 4);
        if (ja < 9u)
          scratch[hl * EP_H + (iabs * 9 + (int)ja) * EP_K + m] = av1[reg] * sc;
      }
    }
  }
  __syncthreads();

  // coalesced write-out: f -> (kk81, hlx, m4)
  for (int f = t; f < 2592; f += NT) {
    const int m4 = f & 3;
    const int hlx = (f >> 2) & 7;
    const int kk81 = f >> 5;  // iabs*9 + jabs
    const float4 v = *(const float4*)(&scratch[hlx * EP_H + kk81 * EP_K + m4 * 4]);
    const int kk = (kk81 + 41) % 81;
    *(float4*)(out + (((size_t)b * DD + kk) * HH + (h0 + hlx)) * WW + w0 +
               m4 * 4) = v;
  }
}

extern "C" void kernel_launch(void* const* d_in, const int* in_sizes, int n_in,
                              void* d_out, int out_size, void* d_ws,
                              size_t ws_size, hipStream_t stream) {
  const float* x1 = (const float*)d_in[0];
  const float* x2 = (const float*)d_in[1];
  float* out = (float*)d_out;

  // zero 256 B of workspace: OOB staging lanes read zeros from here
  hipMemsetAsync(d_ws, 0, 256, stream);

  dim3 grid(WW / 16, HH / 8, 4);  // 16 x 16 x 4 = 1024 blocks
  dim3 block(NT);
  hipLaunchKernelGGL(cost_volume_kernel, grid, block, 0, stream, x1, x2, out,
                     (const float*)d_ws);
}